// Round 8
// baseline (478.939 us; speedup 1.0000x reference)
//
#include <hip/hip_runtime.h>

#define N_NODES 50000
#define N_EDGES 1600000
#define IN_FEATS 128
#define N_HIDDEN 256
#define N_CLASSES 41
#define CHW 16                 // y1 chunk width (floats) = 64 B
#define NCHUNK1 3
#define NB_G 782               // ceil(50000/64) for gather1
#define ECAP 1024
#define NPB 8                  // nodes per block in agg0_mlp

// -------- workspace layout (bytes), 29.2 MB total (< 32.6 MB proven) --------
// y1 aliases rank (rank dead after fill2, before agg0_mlp writes y1)
#define IDEG_OFF  0            // N_NODES int (0.2 MB)
#define ROWS_OFF  204800       // N_NODES+1 int (0.2 MB)
#define RANK_OFF  409600       // N_EDGES int (6.4 MB) -- y1 [3][N][16] f32 (9.6 MB) aliased
#define ESRC_OFF  10009600     // N_EDGES int (6.4 MB)
#define FEATH_OFF 16409600     // N_NODES*IN_FEATS ushort (12.8 MB)

__device__ __forceinline__ unsigned short bf16rne(float x) {
    unsigned b = __float_as_uint(x);
    return (unsigned short)((b + 0x7FFFu + ((b >> 16) & 1u)) >> 16);
}
__device__ __forceinline__ float bf2f(unsigned short u) {
    return __uint_as_float((unsigned)u << 16);
}

// pass 1: degree count + per-edge rank within its dst bucket
__global__ void deg_rank(const int* __restrict__ dst, int* __restrict__ ideg,
                         int* __restrict__ rank) {
    int e = blockIdx.x * blockDim.x + threadIdx.x;
    if (e < N_EDGES) rank[e] = atomicAdd(&ideg[dst[e]], 1);
}

#define SCAN_THREADS 1024
#define SCAN_CHUNK ((N_NODES + SCAN_THREADS - 1) / SCAN_THREADS)   // 49
__global__ __launch_bounds__(SCAN_THREADS) void scan_kernel(
        const int* __restrict__ ideg, int* __restrict__ row_start) {
    __shared__ int part[SCAN_THREADS];
    int t = threadIdx.x;
    int lo = t * SCAN_CHUNK;
    int hi = min(lo + SCAN_CHUNK, N_NODES);
    int s = 0;
    for (int i = lo; i < hi; ++i) s += ideg[i];
    part[t] = s;
    __syncthreads();
    for (int off = 1; off < SCAN_THREADS; off <<= 1) {
        int v = (t >= off) ? part[t - off] : 0;
        __syncthreads();
        if (t >= off) part[t] += v;
        __syncthreads();
    }
    int run = (t == 0) ? 0 : part[t - 1];
    for (int i = lo; i < hi; ++i) {
        row_start[i] = run;
        run += ideg[i];
    }
    if (t == SCAN_THREADS - 1) row_start[N_NODES] = part[SCAN_THREADS - 1];
}

// pass 2: place edges without cursor atomics
__global__ void fill2(const int* __restrict__ src, const int* __restrict__ dst,
                      const int* __restrict__ rank, const int* __restrict__ row_start,
                      int* __restrict__ edge_src) {
    int e = blockIdx.x * blockDim.x + threadIdx.x;
    if (e >= N_EDGES) return;
    edge_src[row_start[dst[e]] + rank[e]] = src[e];
}

// convert features to bf16 (RNE): 4 floats/thread
__global__ void to_bf16(const float* __restrict__ feat, ushort* __restrict__ feat_h) {
    int p = blockIdx.x * 256 + threadIdx.x;
    if (p >= N_NODES * IN_FEATS / 4) return;
    float4 v = ((const float4*)feat)[p];
    ushort4 o;
    o.x = bf16rne(v.x); o.y = bf16rne(v.y);
    o.z = bf16rne(v.z); o.w = bf16rne(v.w);
    ((ushort4*)feat_h)[p] = o;
}

// fused: 8 nodes/block (one wave gathers per node, bf16 rows 256B),
// then relu(x@W1+b1)@W2 -> y1 chunk-major [3][N][16] (b2 deferred)
__global__ __launch_bounds__(512) void agg0_mlp(
        const ushort* __restrict__ feat_h, const int* __restrict__ row_start,
        const int* __restrict__ edge_src,
        const float* __restrict__ W1, const float* __restrict__ b1,
        const float* __restrict__ W2, float* __restrict__ y1) {
    __shared__ float xs[NPB][IN_FEATS];
    __shared__ float hs[NPB][N_HIDDEN];
    const int t = threadIdx.x;
    const int wave = t >> 6, lane = t & 63;
    const int half = lane >> 5, l31 = lane & 31;
    const int node = blockIdx.x * NPB + wave;

    const int start = row_start[node];
    const int deg = row_start[node + 1] - start;

    // ---- gather: 2 edges/iter (half-wave each, ushort4 = 4 bf16 per lane) ----
    float4 acc = make_float4(0.f, 0.f, 0.f, 0.f);
    for (int base = 0; base < deg; base += 64) {
        int cnt = deg - base; if (cnt > 64) cnt = 64;
        int myIdx = 0;
        if (lane < cnt) myIdx = edge_src[start + base + lane];   // coalesced batch
        for (int j = 0; j < cnt; j += 8) {
#pragma unroll
            for (int u = 0; u < 4; ++u) {
                int e = j + 2 * u + half;
                int sn = __shfl(myIdx, e);
                if (e < cnt) {
                    ushort4 v = *(const ushort4*)(feat_h + ((size_t)sn << 7) + (l31 << 2));
                    acc.x += bf2f(v.x); acc.y += bf2f(v.y);
                    acc.z += bf2f(v.z); acc.w += bf2f(v.w);
                }
            }
        }
    }
    acc.x += __shfl_xor(acc.x, 32);
    acc.y += __shfl_xor(acc.y, 32);
    acc.z += __shfl_xor(acc.z, 32);
    acc.w += __shfl_xor(acc.w, 32);
    if (half == 0) {
        float invd = 1.0f / fmaxf((float)deg, 1.0f);
        float4* xp = (float4*)&xs[wave][l31 << 2];
        *xp = make_float4(acc.x * invd, acc.y * invd, acc.z * invd, acc.w * invd);
    }
    __syncthreads();

    // ---- GEMM1: thread owns hidden unit (t&255) for 4 nodes ----
    const int unit = t & 255;
    const int g = (t >> 8) << 2;          // 0 or 4
    float c0 = b1[unit];
    float c1 = c0, c2 = c0, c3 = c0;
#pragma unroll 8
    for (int k = 0; k < IN_FEATS; ++k) {
        float w = W1[k * N_HIDDEN + unit];
        c0 = fmaf(xs[g + 0][k], w, c0);
        c1 = fmaf(xs[g + 1][k], w, c1);
        c2 = fmaf(xs[g + 2][k], w, c2);
        c3 = fmaf(xs[g + 3][k], w, c3);
    }
    hs[g + 0][unit] = fmaxf(c0, 0.f);
    hs[g + 1][unit] = fmaxf(c1, 0.f);
    hs[g + 2][unit] = fmaxf(c2, 0.f);
    hs[g + 3][unit] = fmaxf(c3, 0.f);
    __syncthreads();

    // ---- GEMM2: threads 0..327 -> (node n, class c); write chunk-major ----
    if (t < NPB * N_CLASSES) {
        int n = t / N_CLASSES;
        int c = t - n * N_CLASSES;
        float s = 0.f;
#pragma unroll 8
        for (int k = 0; k < N_HIDDEN; ++k)
            s = fmaf(hs[n][k], W2[k * N_CLASSES + c], s);
        int nd = blockIdx.x * NPB + n;
        y1[((size_t)(c >> 4) * N_NODES + nd) * CHW + (c & 15)] = s;
    } else if (t < NPB * N_CLASSES + NPB * 7) {
        // zero pad columns 41..47 so gather1 reads clean data
        int idx = t - NPB * N_CLASSES;
        int n = idx / 7, c = N_CLASSES + idx % 7;
        int nd = blockIdx.x * NPB + n;
        y1[((size_t)(c >> 4) * N_NODES + nd) * CHW + (c & 15)] = 0.0f;
    }
}

// second aggregation over chunk-major y1 (3.2 MB chunk); /deg + b2
__global__ __launch_bounds__(256) void gather1(
        const float* __restrict__ y1, int chunk,
        const int* __restrict__ row_start, const int* __restrict__ edge_src,
        const float* __restrict__ b2, float* __restrict__ out) {
    __shared__ int eidx[4][ECAP];
    const int t = threadIdx.x;
    const int w = t >> 6, lane = t & 63;
    const int g = lane >> 2, l4 = lane & 3;
    const int n0w = blockIdx.x * 64 + w * 16;

    int v = row_start[min(n0w + lane, N_NODES)];
    const int gbase = __shfl(v, 0);
    const int sg = __shfl(v, g);
    const int cnt = __shfl(v, g + 1) - sg;
    const int sl = sg - gbase;
    const int tot = __shfl(v, 16) - gbase;

    for (int i = lane; i < min(tot, ECAP); i += 64)
        eidx[w][i] = edge_src[gbase + i];
    __syncthreads();

    int maxc = cnt;
#pragma unroll
    for (int off = 32; off; off >>= 1) maxc = max(maxc, __shfl_xor(maxc, off));

    const float* fp = y1 + (size_t)chunk * N_NODES * CHW + l4 * 4;
    float4 a0 = make_float4(0.f, 0.f, 0.f, 0.f);
    float4 a1 = make_float4(0.f, 0.f, 0.f, 0.f);
    for (int k = 0; k < maxc; k += 2) {
        if (k < cnt) {
            int p = sl + k;
            int idx = (p < ECAP) ? eidx[w][p] : edge_src[gbase + p];
            float4 vv = *(const float4*)(fp + (size_t)idx * CHW);
            a0.x += vv.x; a0.y += vv.y; a0.z += vv.z; a0.w += vv.w;
        }
        if (k + 1 < cnt) {
            int p = sl + k + 1;
            int idx = (p < ECAP) ? eidx[w][p] : edge_src[gbase + p];
            float4 vv = *(const float4*)(fp + (size_t)idx * CHW);
            a1.x += vv.x; a1.y += vv.y; a1.z += vv.z; a1.w += vv.w;
        }
    }
    const int node = n0w + g;
    if (node < N_NODES) {
        float invd = 1.0f / fmaxf((float)cnt, 1.0f);
        float r[4] = {a0.x + a1.x, a0.y + a1.y, a0.z + a1.z, a0.w + a1.w};
        const int cbase = chunk * CHW + l4 * 4;
#pragma unroll
        for (int i = 0; i < 4; ++i) {
            int col = cbase + i;
            if (col < N_CLASSES)
                out[(size_t)node * N_CLASSES + col] = r[i] * invd + b2[col];
        }
    }
}

extern "C" void kernel_launch(void* const* d_in, const int* in_sizes, int n_in,
                              void* d_out, int out_size, void* d_ws, size_t ws_size,
                              hipStream_t stream) {
    const float* feat = (const float*)d_in[0];
    const int*   src  = (const int*)d_in[1];
    const int*   dst  = (const int*)d_in[2];
    const float* W1   = (const float*)d_in[3];
    const float* b1   = (const float*)d_in[4];
    const float* W2   = (const float*)d_in[5];
    const float* b2   = (const float*)d_in[6];
    float* out = (float*)d_out;

    char* ws = (char*)d_ws;
    int*    ideg      = (int*)(ws + IDEG_OFF);
    int*    row_start = (int*)(ws + ROWS_OFF);
    int*    rank      = (int*)(ws + RANK_OFF);
    int*    edge_src  = (int*)(ws + ESRC_OFF);
    ushort* feat_h    = (ushort*)(ws + FEATH_OFF);
    float*  y1        = (float*)(ws + RANK_OFF);   // aliases rank (dead after fill2)

    hipMemsetAsync(ideg, 0, N_NODES * 4, stream);
    to_bf16<<<(N_NODES * IN_FEATS / 4 + 255) / 256, 256, 0, stream>>>(feat, feat_h);
    deg_rank<<<(N_EDGES + 255) / 256, 256, 0, stream>>>(dst, ideg, rank);
    scan_kernel<<<1, SCAN_THREADS, 0, stream>>>(ideg, row_start);
    fill2<<<(N_EDGES + 255) / 256, 256, 0, stream>>>(src, dst, rank, row_start, edge_src);

    agg0_mlp<<<N_NODES / NPB, 512, 0, stream>>>(feat_h, row_start, edge_src, W1, b1, W2, y1);

    for (int c = 0; c < NCHUNK1; ++c)
        gather1<<<NB_G, 256, 0, stream>>>(y1, c, row_start, edge_src, b2, out);
}

// Round 9
// 323.295 us; speedup vs baseline: 1.4814x; 1.4814x over previous
//
#include <hip/hip_runtime.h>

#define N_NODES 50000
#define N_EDGES 1600000
#define IN_FEATS 128
#define N_HIDDEN 256
#define N_CLASSES 41
#define CHW 16                 // y1 chunk width (floats) = 64 B
#define NCHUNK1 3
#define NB_G 782               // ceil(50000/64) for gather1
#define ECAP 1024
#define NPB 16                 // nodes per block in agg0_mlp (3125 blocks)

typedef short  bf16x8 __attribute__((ext_vector_type(8)));
typedef float  f32x4  __attribute__((ext_vector_type(4)));

// -------- workspace layout (bytes), 29.3 MB total (< 32.6 MB proven) --------
#define IDEG_OFF  0            // N_NODES int
#define ROWS_OFF  204800       // N_NODES+1 int
#define RANK_OFF  409600       // N_EDGES int (6.4 MB); y1 [3][N][16] f32 (9.6MB) aliased
#define ESRC_OFF  10009600     // N_EDGES int (6.4 MB)
#define FEATH_OFF 16409600     // N_NODES*IN_FEATS ushort (12.8 MB)
#define W1P_OFF   29209600     // 16*4*64*8 bf16 = 64 KB (MFMA B-fragment layout)
#define W2P_OFF   29275136     // 3*8*64*8 bf16 = 24 KB

__device__ __forceinline__ unsigned short bf16rne(float x) {
    unsigned b = __float_as_uint(x);
    return (unsigned short)((b + 0x7FFFu + ((b >> 16) & 1u)) >> 16);
}
__device__ __forceinline__ float bf2f(unsigned short u) {
    return __uint_as_float((unsigned)u << 16);
}

__global__ void deg_rank(const int* __restrict__ dst, int* __restrict__ ideg,
                         int* __restrict__ rank) {
    int e = blockIdx.x * blockDim.x + threadIdx.x;
    if (e < N_EDGES) rank[e] = atomicAdd(&ideg[dst[e]], 1);
}

#define SCAN_THREADS 1024
#define SCAN_CHUNK ((N_NODES + SCAN_THREADS - 1) / SCAN_THREADS)   // 49
__global__ __launch_bounds__(SCAN_THREADS) void scan_kernel(
        const int* __restrict__ ideg, int* __restrict__ row_start) {
    __shared__ int part[SCAN_THREADS];
    int t = threadIdx.x;
    int lo = t * SCAN_CHUNK;
    int hi = min(lo + SCAN_CHUNK, N_NODES);
    int s = 0;
    for (int i = lo; i < hi; ++i) s += ideg[i];
    part[t] = s;
    __syncthreads();
    for (int off = 1; off < SCAN_THREADS; off <<= 1) {
        int v = (t >= off) ? part[t - off] : 0;
        __syncthreads();
        if (t >= off) part[t] += v;
        __syncthreads();
    }
    int run = (t == 0) ? 0 : part[t - 1];
    for (int i = lo; i < hi; ++i) {
        row_start[i] = run;
        run += ideg[i];
    }
    if (t == SCAN_THREADS - 1) row_start[N_NODES] = part[SCAN_THREADS - 1];
}

__global__ void fill2(const int* __restrict__ src, const int* __restrict__ dst,
                      const int* __restrict__ rank, const int* __restrict__ row_start,
                      int* __restrict__ edge_src) {
    int e = blockIdx.x * blockDim.x + threadIdx.x;
    if (e >= N_EDGES) return;
    edge_src[row_start[dst[e]] + rank[e]] = src[e];
}

// convert features to bf16 (RNE): 4 floats/thread
__global__ void to_bf16(const float* __restrict__ feat, ushort* __restrict__ feat_h) {
    int p = blockIdx.x * 256 + threadIdx.x;
    if (p >= N_NODES * IN_FEATS / 4) return;
    float4 v = ((const float4*)feat)[p];
    ushort4 o;
    o.x = bf16rne(v.x); o.y = bf16rne(v.y);
    o.z = bf16rne(v.z); o.w = bf16rne(v.w);
    ((ushort4*)feat_h)[p] = o;
}

// pack W1 [128][256] f32 -> MFMA B-fragment bf16: [ntile(16)][kstep(4)][lane(64)][8]
// B[k][n]: n = nt*16 + (lane&15), k = ks*32 + (lane>>4)*8 + j
__global__ void pack_w1(const float* __restrict__ W1, ushort* __restrict__ w1p) {
    int idx = blockIdx.x * 256 + threadIdx.x;          // < 32768
    int j = idx & 7, l = (idx >> 3) & 63, ks = (idx >> 9) & 3, nt = idx >> 11;
    int k = ks * 32 + ((l >> 4) * 8) + j;
    int n = nt * 16 + (l & 15);
    w1p[idx] = bf16rne(W1[k * N_HIDDEN + n]);
}

// pack W2 [256][41] f32 -> [ntile(3)][kstep(8)][lane(64)][8], cols 41..47 zero
__global__ void pack_w2(const float* __restrict__ W2, ushort* __restrict__ w2p) {
    int idx = blockIdx.x * 256 + threadIdx.x;          // < 12288
    int j = idx & 7, l = (idx >> 3) & 63, ks = (idx >> 9) & 7, nt = idx >> 12;
    int k = ks * 32 + ((l >> 4) * 8) + j;
    int n = nt * 16 + (l & 15);
    w2p[idx] = (n < N_CLASSES) ? bf16rne(W2[k * N_CLASSES + n]) : (ushort)0;
}

// fused: gather 16 nodes (2/wave, bf16) -> GEMM1 MFMA -> relu -> GEMM2 MFMA
// y1 chunk-major [3][N][16] f32 (b2 deferred to gather1)
__global__ __launch_bounds__(512) void agg0_mlp(
        const ushort* __restrict__ feat_h, const int* __restrict__ row_start,
        const int* __restrict__ edge_src,
        const ushort* __restrict__ w1p, const float* __restrict__ b1,
        const ushort* __restrict__ w2p, float* __restrict__ y1) {
    __shared__ ushort xs[NPB][136];    // bf16 aggregated features, row pad 16 B
    __shared__ ushort hs[NPB][264];    // bf16 hidden, row pad 16 B
    const int t = threadIdx.x;
    const int w = t >> 6, lane = t & 63;
    const int half = lane >> 5, l31 = lane & 31;
    const int node0 = blockIdx.x * NPB;

    // ---- gather: each wave aggregates 2 nodes (half-wave = 1 edge, ushort4/lane) ----
    for (int i = 0; i < 2; ++i) {
        const int nl = w * 2 + i;
        const int node = node0 + nl;
        const int start = row_start[node];
        const int deg = row_start[node + 1] - start;
        float4 acc = make_float4(0.f, 0.f, 0.f, 0.f);
        for (int base = 0; base < deg; base += 64) {
            int cnt = deg - base; if (cnt > 64) cnt = 64;
            int myIdx = 0;
            if (lane < cnt) myIdx = edge_src[start + base + lane];
            for (int j = 0; j < cnt; j += 8) {
#pragma unroll
                for (int u = 0; u < 4; ++u) {
                    int e = j + 2 * u + half;
                    int sn = __shfl(myIdx, e);
                    if (e < cnt) {
                        ushort4 v = *(const ushort4*)(feat_h + ((size_t)sn << 7) + (l31 << 2));
                        acc.x += bf2f(v.x); acc.y += bf2f(v.y);
                        acc.z += bf2f(v.z); acc.w += bf2f(v.w);
                    }
                }
            }
        }
        acc.x += __shfl_xor(acc.x, 32);
        acc.y += __shfl_xor(acc.y, 32);
        acc.z += __shfl_xor(acc.z, 32);
        acc.w += __shfl_xor(acc.w, 32);
        if (half == 0) {
            float invd = 1.0f / fmaxf((float)deg, 1.0f);
            ushort4 sv;
            sv.x = bf16rne(acc.x * invd); sv.y = bf16rne(acc.y * invd);
            sv.z = bf16rne(acc.z * invd); sv.w = bf16rne(acc.w * invd);
            *(ushort4*)&xs[nl][l31 * 4] = sv;
        }
    }
    __syncthreads();

    // ---- GEMM1: M=16 nodes, N=256 units, K=128; wave w owns N-tiles {2w, 2w+1} ----
    // A-frag: lane holds xs[lane&15][ks*32 + (lane>>4)*8 .. +7]
    bf16x8 afr[4];
#pragma unroll
    for (int ks = 0; ks < 4; ++ks)
        afr[ks] = *(const bf16x8*)&xs[lane & 15][ks * 32 + ((lane >> 4) * 8)];

    f32x4 c1[2] = {{0.f, 0.f, 0.f, 0.f}, {0.f, 0.f, 0.f, 0.f}};
#pragma unroll
    for (int nt = 0; nt < 2; ++nt) {
#pragma unroll
        for (int ks = 0; ks < 4; ++ks) {
            bf16x8 bfr = *(const bf16x8*)(w1p + (((w * 2 + nt) * 4 + ks) * 64 + lane) * 8);
            c1[nt] = __builtin_amdgcn_mfma_f32_16x16x32_bf16(afr[ks], bfr, c1[nt], 0, 0, 0);
        }
    }
    // bias + relu -> hs (C layout: col=lane&15 (unit), row=(lane>>4)*4+r (node))
#pragma unroll
    for (int nt = 0; nt < 2; ++nt) {
        float bb = b1[(w * 2 + nt) * 16 + (lane & 15)];
#pragma unroll
        for (int r = 0; r < 4; ++r) {
            float hv = fmaxf(c1[nt][r] + bb, 0.f);
            hs[(lane >> 4) * 4 + r][(w * 2 + nt) * 16 + (lane & 15)] = bf16rne(hv);
        }
    }
    __syncthreads();

    // ---- GEMM2: M=16 nodes, N=48 classes(pad), K=256; waves 0..2 own one N-tile ----
    if (w < 3) {
        f32x4 c2 = {0.f, 0.f, 0.f, 0.f};
#pragma unroll
        for (int ks = 0; ks < 8; ++ks) {
            bf16x8 a2 = *(const bf16x8*)&hs[lane & 15][ks * 32 + ((lane >> 4) * 8)];
            bf16x8 b2f = *(const bf16x8*)(w2p + ((w * 8 + ks) * 64 + lane) * 8);
            c2 = __builtin_amdgcn_mfma_f32_16x16x32_bf16(a2, b2f, c2, 0, 0, 0);
        }
#pragma unroll
        for (int r = 0; r < 4; ++r) {
            int node = node0 + (lane >> 4) * 4 + r;
            y1[((size_t)w * N_NODES + node) * CHW + (lane & 15)] = c2[r];
        }
    }
}

// second aggregation over chunk-major y1 (3.2 MB chunk); /deg + b2
__global__ __launch_bounds__(256) void gather1(
        const float* __restrict__ y1, int chunk,
        const int* __restrict__ row_start, const int* __restrict__ edge_src,
        const float* __restrict__ b2, float* __restrict__ out) {
    __shared__ int eidx[4][ECAP];
    const int t = threadIdx.x;
    const int w = t >> 6, lane = t & 63;
    const int g = lane >> 2, l4 = lane & 3;
    const int n0w = blockIdx.x * 64 + w * 16;

    int v = row_start[min(n0w + lane, N_NODES)];
    const int gbase = __shfl(v, 0);
    const int sg = __shfl(v, g);
    const int cnt = __shfl(v, g + 1) - sg;
    const int sl = sg - gbase;
    const int tot = __shfl(v, 16) - gbase;

    for (int i = lane; i < min(tot, ECAP); i += 64)
        eidx[w][i] = edge_src[gbase + i];
    __syncthreads();

    int maxc = cnt;
#pragma unroll
    for (int off = 32; off; off >>= 1) maxc = max(maxc, __shfl_xor(maxc, off));

    const float* fp = y1 + (size_t)chunk * N_NODES * CHW + l4 * 4;
    float4 a0 = make_float4(0.f, 0.f, 0.f, 0.f);
    float4 a1 = make_float4(0.f, 0.f, 0.f, 0.f);
    for (int k = 0; k < maxc; k += 2) {
        if (k < cnt) {
            int p = sl + k;
            int idx = (p < ECAP) ? eidx[w][p] : edge_src[gbase + p];
            float4 vv = *(const float4*)(fp + (size_t)idx * CHW);
            a0.x += vv.x; a0.y += vv.y; a0.z += vv.z; a0.w += vv.w;
        }
        if (k + 1 < cnt) {
            int p = sl + k + 1;
            int idx = (p < ECAP) ? eidx[w][p] : edge_src[gbase + p];
            float4 vv = *(const float4*)(fp + (size_t)idx * CHW);
            a1.x += vv.x; a1.y += vv.y; a1.z += vv.z; a1.w += vv.w;
        }
    }
    const int node = n0w + g;
    if (node < N_NODES) {
        float invd = 1.0f / fmaxf((float)cnt, 1.0f);
        float r[4] = {a0.x + a1.x, a0.y + a1.y, a0.z + a1.z, a0.w + a1.w};
        const int cbase = chunk * CHW + l4 * 4;
#pragma unroll
        for (int i = 0; i < 4; ++i) {
            int col = cbase + i;
            if (col < N_CLASSES)
                out[(size_t)node * N_CLASSES + col] = r[i] * invd + b2[col];
        }
    }
}

extern "C" void kernel_launch(void* const* d_in, const int* in_sizes, int n_in,
                              void* d_out, int out_size, void* d_ws, size_t ws_size,
                              hipStream_t stream) {
    const float* feat = (const float*)d_in[0];
    const int*   src  = (const int*)d_in[1];
    const int*   dst  = (const int*)d_in[2];
    const float* W1   = (const float*)d_in[3];
    const float* b1   = (const float*)d_in[4];
    const float* W2   = (const float*)d_in[5];
    const float* b2   = (const float*)d_in[6];
    float* out = (float*)d_out;

    char* ws = (char*)d_ws;
    int*    ideg      = (int*)(ws + IDEG_OFF);
    int*    row_start = (int*)(ws + ROWS_OFF);
    int*    rank      = (int*)(ws + RANK_OFF);
    int*    edge_src  = (int*)(ws + ESRC_OFF);
    ushort* feat_h    = (ushort*)(ws + FEATH_OFF);
    ushort* w1p       = (ushort*)(ws + W1P_OFF);
    ushort* w2p       = (ushort*)(ws + W2P_OFF);
    float*  y1        = (float*)(ws + RANK_OFF);   // aliases rank (dead after fill2)

    hipMemsetAsync(ideg, 0, N_NODES * 4, stream);
    to_bf16<<<(N_NODES * IN_FEATS / 4 + 255) / 256, 256, 0, stream>>>(feat, feat_h);
    pack_w1<<<128, 256, 0, stream>>>(W1, w1p);
    pack_w2<<<48, 256, 0, stream>>>(W2, w2p);
    deg_rank<<<(N_EDGES + 255) / 256, 256, 0, stream>>>(dst, ideg, rank);
    scan_kernel<<<1, SCAN_THREADS, 0, stream>>>(ideg, row_start);
    fill2<<<(N_EDGES + 255) / 256, 256, 0, stream>>>(src, dst, rank, row_start, edge_src);

    agg0_mlp<<<N_NODES / NPB, 512, 0, stream>>>(feat_h, row_start, edge_src,
                                                w1p, b1, w2p, y1);

    for (int c = 0; c < NCHUNK1; ++c)
        gather1<<<NB_G, 256, 0, stream>>>(y1, c, row_start, edge_src, b2, out);
}